// Round 14
// baseline (197.037 us; speedup 1.0000x reference)
//
#include <hip/hip_runtime.h>

// Conv3d(8->32, k=3, VALID) + bias + HardSwish + GroupNorm(4) + mean pool.
// R10 (resubmit x7; GPU acquisition timed out, never measured):
// R7/R9 (dep-distance-2 MFMA chains) both ~105-117us; prev-session R5
// (dep-distance-4) was ~82us conv. Per-SIMD 16x16x32 MFMA throughput ~19cyc
// -> dep-2 chains starve the matrix pipe at 4 waves/SIMD. Fix, keeping R9's
// contiguous ds_read_b128 B-fragments:
//  - phase A per y: xt{0,1} together = 4 independent chains (aH0,aH1,aL0,aL1)
//  - phase B per y-pair: xt2 for y,y+1 = 4 independent chains
//  - s_setprio(1) around MFMA bursts (no barriers in loop -> phase diversity)
//  - gn_finalize folded into conv's LAST block (atomic cnt + atomic reads of
//    ws1/ws2) -> 2 dispatches total instead of 3 (~15-20us fixed overhead cut)
// launch_bounds semantics (measured R8/R9): arg2 = min BLOCKS/CU (CUDA-style).
// (512,2) -> 128-VGPR cap, 16 waves/CU.

#define IN 48
#define IN2 2304
#define IN3 110592
#define OUTD 46
#define RS 200            // row stride in dwords (48*4 used + 8 pad)
#define NROW 60           // 6 z-rows x 10 y-rows
#define WPK_OFF 1024      // dword offset of packed-weight table inside ws
#define CNT_OFF 8192      // dword offset of the block-completion counter
#define NBLK (16*12*6)

typedef short v8s    __attribute__((ext_vector_type(8)));
typedef float f32x4  __attribute__((ext_vector_type(4)));
typedef int   i32x4  __attribute__((ext_vector_type(4)));

__device__ __forceinline__ unsigned short f2bf(float f) {
    unsigned u = __builtin_bit_cast(unsigned, f);
    return (unsigned short)((u + 0x7fffu + ((u >> 16) & 1u)) >> 16);   // RNE
}
__device__ __forceinline__ float bf2f(unsigned short h) {
    unsigned u = ((unsigned)h) << 16;
    return __builtin_bit_cast(float, u);
}

// A fragments for 16x16x32, co-split. Layout: [coh][hl][c 0..6][lane][4 dw].
// Lane: co_local = lane&15, kq = lane>>4 -> tap tau = 4c+kq; dword j = ci pair
// (2j lo, 2j+1 hi). tau>=27 -> zero. Also zeroes ws1/ws2 and cnt.
__global__ __launch_bounds__(256) void pack_weights(
    const float* __restrict__ w, unsigned* __restrict__ wpk,
    float* __restrict__ wsz)
{
    int gid = blockIdx.x * 256 + threadIdx.x;
    if (gid < 1024) wsz[gid] = 0.f;
    if (gid == 1024) ((unsigned*)wsz)[CNT_OFF] = 0u;
    if (gid >= 1792) return;
    int lane = gid & 63;
    int rest = gid >> 6;          // 0..27
    int c   = rest % 7;
    int hl  = (rest / 7) & 1;     // 0 = hi bf16, 1 = lo (residual)
    int coh = rest / 14;
    int n = lane & 15, kq = lane >> 4;
    int co  = coh * 16 + n;
    int tau = 4 * c + kq;
    unsigned o[4];
    #pragma unroll
    for (int j = 0; j < 4; ++j) {
        if (tau >= 27) { o[j] = 0u; continue; }
        float w0 = w[(co * 8 + 2 * j) * 27 + tau];
        float w1 = w[(co * 8 + 2 * j + 1) * 27 + tau];
        unsigned short b0 = f2bf(w0), b1 = f2bf(w1);
        if (hl) {
            b0 = f2bf(w0 - bf2f(b0));
            b1 = f2bf(w1 - bf2f(b1));
        }
        o[j] = ((unsigned)b1 << 16) | b0;
    }
    *(i32x4*)(wpk + (((coh * 2 + hl) * 7 + c) * 64 + lane) * 4) =
        (i32x4){(int)o[0], (int)o[1], (int)o[2], (int)o[3]};
}

__global__ __launch_bounds__(512, 2) void conv_hs_mfma(
    const float* __restrict__ x, const unsigned* __restrict__ wpk,
    const float* __restrict__ bias, float* __restrict__ ws1, float* __restrict__ ws2,
    unsigned* __restrict__ cnt, const float* __restrict__ gnw,
    const float* __restrict__ gnb, float* __restrict__ out)
{
    __shared__ unsigned xdw[NROW * RS];   // 48 KB: [row 60][e*4 + cipair] linear
    __shared__ float s1b[32], s2b[32];
    __shared__ unsigned slast;

    const int tid  = threadIdx.x;
    const int lane = tid & 63;
    const int wv   = tid >> 6;          // 0..7
    const int zw   = wv & 3;            // z offset within tile
    const int coh  = wv >> 2;           // co half (0: co 0-15, 1: co 16-31)
    const int n    = lane & 15;         // A row (co_local) / B col (x)
    const int kq   = lane >> 4;         // k-quarter -> tap 4c+kq

    const int blk = blockIdx.x;
    const int b   = blk / 72;
    const int r0  = blk - b * 72;
    const int zb  = r0 / 6;
    const int yb  = r0 - zb * 6;
    const int z0  = zb * 4, y0 = yb * 8;
    const int z   = z0 + zw;

    if (tid < 32)      s1b[tid] = 0.f;
    else if (tid < 64) s2b[tid - 32] = 0.f;

    // A fragments: 14 coalesced 16B loads; 56 VGPRs, stay resident.
    i32x4 Ah[7], Al[7];
    #pragma unroll
    for (int c = 0; c < 7; ++c) {
        Ah[c] = *(const i32x4*)(wpk + (((coh * 2 + 0) * 7 + c) * 64 + lane) * 4);
        Al[c] = *(const i32x4*)(wpk + (((coh * 2 + 1) * 7 + c) * 64 + lane) * 4);
    }

    // C/D layout (16x16): col = n, row(co_local) = kq*4 + i
    float bias_r[4];
    #pragma unroll
    for (int i = 0; i < 4; ++i)
        bias_r[i] = bias[coh * 16 + kq * 4 + i];

    // Per-lane LDS base per chunk: tau = min(4c+kq, 26) (pad slot -> A=0).
    const char* bc[7];
    #pragma unroll
    for (int c = 0; c < 7; ++c) {
        int tau = 4 * c + kq; if (tau > 26) tau = 26;
        const int toff = ((tau / 9) * 10 + ((tau % 9) / 3)) * (RS * 4)
                       + (tau % 3) * 16;
        bc[c] = (const char*)xdw + zw * (10 * RS * 4) + n * 16 + toff;
    }

    // ---- stage x tile, bf16 ci-pair packed, linear layout ----
    {
        const int q  = tid & 3;
        const int zh = (tid >> 2) & 1;
        const int e  = tid >> 3;          // 0..63, active < 48
        if (e < 48) {
            const float* p0 = x + (b * 8 + 2 * q) * IN3 + e;
            const float* p1 = p0 + IN3;
            unsigned* dst = xdw + e * 4 + q;
            #pragma unroll
            for (int zr2 = 0; zr2 < 3; ++zr2) {
                const int zr = zh * 3 + zr2;
                const int gz = min(z0 + zr, IN - 1);
                #pragma unroll
                for (int yr = 0; yr < 10; ++yr) {
                    const int gy = min(y0 + yr, IN - 1);
                    const int off = gz * IN2 + gy * IN;
                    float f0 = p0[off], f1 = p1[off];
                    dst[(zr * 10 + yr) * RS] = ((unsigned)f2bf(f1) << 16) | f2bf(f0);
                }
            }
        }
    }
    __syncthreads();

    float t1[4] = {0, 0, 0, 0};
    float t2[4] = {0, 0, 0, 0};

    if (z < OUTD) {
        const int ymax = min(8, OUTD - y0);
        #pragma unroll
        for (int yy = 0; yy < 8; yy += 2) {
            // ---- phase A: xt0 + xt1, 4 independent MFMA chains, per y ----
            #pragma unroll
            for (int ys = 0; ys < 2; ++ys) {
                const int y   = yy + ys;
                const int yb4 = y * (RS * 4);
                f32x4 aH0, aL0, aH1, aL1;
                #pragma unroll
                for (int i = 0; i < 4; ++i) {
                    aH0[i] = bias_r[i]; aL0[i] = 0.f;
                    aH1[i] = bias_r[i]; aL1[i] = 0.f;
                }
                __builtin_amdgcn_s_setprio(1);
                #pragma unroll
                for (int c = 0; c < 7; ++c) {
                    i32x4 d0 = *(const i32x4*)(bc[c] + yb4);
                    i32x4 d1 = *(const i32x4*)(bc[c] + yb4 + 256);
                    v8s B0 = __builtin_bit_cast(v8s, d0);
                    v8s B1 = __builtin_bit_cast(v8s, d1);
                    v8s WH = __builtin_bit_cast(v8s, Ah[c]);
                    v8s WL = __builtin_bit_cast(v8s, Al[c]);
                    aH0 = __builtin_amdgcn_mfma_f32_16x16x32_bf16(WH, B0, aH0, 0, 0, 0);
                    aH1 = __builtin_amdgcn_mfma_f32_16x16x32_bf16(WH, B1, aH1, 0, 0, 0);
                    aL0 = __builtin_amdgcn_mfma_f32_16x16x32_bf16(WL, B0, aL0, 0, 0, 0);
                    aL1 = __builtin_amdgcn_mfma_f32_16x16x32_bf16(WL, B1, aL1, 0, 0, 0);
                }
                __builtin_amdgcn_s_setprio(0);
                const bool oky = y < ymax;   // cols 0..31 always < 46
                #pragma unroll
                for (int i = 0; i < 4; ++i) {
                    float v0 = aH0[i] + aL0[i];
                    float u0 = fminf(fmaxf(v0 + 3.0f, 0.0f), 6.0f);
                    float h0 = v0 * u0 * (1.0f / 6.0f);
                    h0 = oky ? h0 : 0.f;
                    t1[i] += h0; t2[i] = fmaf(h0, h0, t2[i]);
                    float v1 = aH1[i] + aL1[i];
                    float u1 = fminf(fmaxf(v1 + 3.0f, 0.0f), 6.0f);
                    float h1 = v1 * u1 * (1.0f / 6.0f);
                    h1 = oky ? h1 : 0.f;
                    t1[i] += h1; t2[i] = fmaf(h1, h1, t2[i]);
                }
            }
            // ---- phase B: xt2 for y-pair (yy, yy+1), 4 independent chains ----
            {
                const int ya4 = yy * (RS * 4);
                const int yb4 = (yy + 1) * (RS * 4);
                f32x4 aHa, aLa, aHb, aLb;
                #pragma unroll
                for (int i = 0; i < 4; ++i) {
                    aHa[i] = bias_r[i]; aLa[i] = 0.f;
                    aHb[i] = bias_r[i]; aLb[i] = 0.f;
                }
                __builtin_amdgcn_s_setprio(1);
                #pragma unroll
                for (int c = 0; c < 7; ++c) {
                    i32x4 da = *(const i32x4*)(bc[c] + ya4 + 512);
                    i32x4 db = *(const i32x4*)(bc[c] + yb4 + 512);
                    v8s Ba = __builtin_bit_cast(v8s, da);
                    v8s Bb = __builtin_bit_cast(v8s, db);
                    v8s WH = __builtin_bit_cast(v8s, Ah[c]);
                    v8s WL = __builtin_bit_cast(v8s, Al[c]);
                    aHa = __builtin_amdgcn_mfma_f32_16x16x32_bf16(WH, Ba, aHa, 0, 0, 0);
                    aHb = __builtin_amdgcn_mfma_f32_16x16x32_bf16(WH, Bb, aHb, 0, 0, 0);
                    aLa = __builtin_amdgcn_mfma_f32_16x16x32_bf16(WL, Ba, aLa, 0, 0, 0);
                    aLb = __builtin_amdgcn_mfma_f32_16x16x32_bf16(WL, Bb, aLb, 0, 0, 0);
                }
                __builtin_amdgcn_s_setprio(0);
                const bool okx = n < 14;              // col 32+n < 46
                const bool oka = okx && (yy < ymax);
                const bool okb = okx && (yy + 1 < ymax);
                #pragma unroll
                for (int i = 0; i < 4; ++i) {
                    float va = aHa[i] + aLa[i];
                    float ua = fminf(fmaxf(va + 3.0f, 0.0f), 6.0f);
                    float ha = va * ua * (1.0f / 6.0f);
                    ha = oka ? ha : 0.f;
                    t1[i] += ha; t2[i] = fmaf(ha, ha, t2[i]);
                    float vb = aHb[i] + aLb[i];
                    float ub = fminf(fmaxf(vb + 3.0f, 0.0f), 6.0f);
                    float hb = vb * ub * (1.0f / 6.0f);
                    hb = okb ? hb : 0.f;
                    t1[i] += hb; t2[i] = fmaf(hb, hb, t2[i]);
                }
            }
        }
    }

    // reduce over the 16 col-lanes (n); channel is per-(kq, i, coh)
    #pragma unroll
    for (int i = 0; i < 4; ++i) {
        #pragma unroll
        for (int k = 1; k < 16; k <<= 1) {
            t1[i] += __shfl_xor(t1[i], k, 64);
            t2[i] += __shfl_xor(t2[i], k, 64);
        }
    }
    if (n == 0) {
        #pragma unroll
        for (int i = 0; i < 4; ++i) {
            const int co = coh * 16 + kq * 4 + i;
            atomicAdd(&s1b[co], t1[i]);
            atomicAdd(&s2b[co], t2[i]);
        }
    }
    __syncthreads();
    if (tid < 32)       atomicAdd(&ws1[b * 32 + tid], s1b[tid]);
    else if (tid < 64)  atomicAdd(&ws2[b * 32 + (tid - 32)], s2b[tid - 32]);

    // ---- last block finalizes GroupNorm + pool (saves a dispatch) ----
    __syncthreads();   // barrier drains this block's ws atomics (vmcnt 0)
    if (tid == 0) {
        __threadfence();
        slast = (atomicAdd(cnt, 1u) == NBLK - 1) ? 1u : 0u;
    }
    __syncthreads();
    if (slast) {
        const int c = tid & 31;
        float s1 = atomicAdd(&ws1[tid], 0.f);   // atomic read: device-coherent
        float s2 = atomicAdd(&ws2[tid], 0.f);
        float g1 = s1, g2 = s2;
        #pragma unroll
        for (int k = 1; k < 8; k <<= 1) {
            g1 += __shfl_xor(g1, k, 64);
            g2 += __shfl_xor(g2, k, 64);
        }
        const float Nsp  = 46.0f * 46.0f * 46.0f;
        const float invN = 1.0f / (8.0f * Nsp);
        float mean = g1 * invN;
        float var  = fmaxf(g2 * invN - mean * mean, 0.0f);
        float rstd = rsqrtf(var + 1e-5f);
        float mc   = s1 * (1.0f / Nsp);
        out[tid] = (mc - mean) * rstd * gnw[c] + gnb[c];
    }
}

extern "C" void kernel_launch(void* const* d_in, const int* in_sizes, int n_in,
                              void* d_out, int out_size, void* d_ws, size_t ws_size,
                              hipStream_t stream) {
    const float* x    = (const float*)d_in[0];
    const float* w    = (const float*)d_in[1];
    const float* bias = (const float*)d_in[2];
    const float* gnw  = (const float*)d_in[3];
    const float* gnb  = (const float*)d_in[4];
    float* out = (float*)d_out;
    float* ws1 = (float*)d_ws;
    float* ws2 = ws1 + 512;
    unsigned* wpk = (unsigned*)d_ws + WPK_OFF;   // 7168 dwords
    unsigned* cnt = (unsigned*)d_ws + CNT_OFF;

    pack_weights<<<dim3(7), dim3(256), 0, stream>>>(w, wpk, ws1);
    conv_hs_mfma<<<dim3(NBLK), dim3(512), 0, stream>>>(
        x, wpk, bias, ws1, ws2, cnt, gnw, gnb, out);
}

// Round 15
// 146.311 us; speedup vs baseline: 1.3467x; 1.3467x over previous
//
#include <hip/hip_runtime.h>

// Conv3d(8->32, k=3, VALID) + bias + HardSwish + GroupNorm(4) + mean pool.
// R11 = REVERT to prev-session R5 (proven best: 147.5us total), counters never
// captured for it. Session ladder: R5 147.5 -> R7 181 -> R9 184 -> R10 197 --
// every structural change regressed. R10's A/B killed the dep-chain theory
// (MfmaUtil DOWN at dep-4). R5's distinguishing features: 4z x 4y tiles,
// 2304 blocks x 256 threads, 28.8KB LDS (5 blocks/CU residency vs my 3),
// short staging phase per barrier. Only change vs R5: ws zeroing folded into
// pack_weights (pattern proven R8-R10), memset dispatch dropped.
// Diagnostic targets: WRITE_SIZE (spill?), OccupancyPercent (residency?).

#define IN 48
#define IN2 2304
#define IN3 110592
#define OUTD 46
#define RS 200            // row stride in dwords (48*4 used + pad for masked overread)
#define NROW 36
#define WPK_OFF 1024      // dword offset of packed-weight table inside ws

typedef short v8s   __attribute__((ext_vector_type(8)));
typedef float f32x4 __attribute__((ext_vector_type(4)));
typedef int   i32x4 __attribute__((ext_vector_type(4)));

__device__ __forceinline__ unsigned short f2bf(float f) {
    unsigned u = __builtin_bit_cast(unsigned, f);
    return (unsigned short)((u + 0x7fffu + ((u >> 16) & 1u)) >> 16);   // RNE
}
__device__ __forceinline__ float bf2f(unsigned short h) {
    unsigned u = ((unsigned)h) << 16;
    return __builtin_bit_cast(float, u);
}

// One-time: build lane-exact A fragments. Layout: [hh=2h+hl][t 0..6][lane 0..63][4 dw]
// hl: 0 = hi bf16, 1 = lo bf16 (residual). tau = 4t+j; tau>=27 -> zero weight.
// Also zeroes ws1/ws2 (gid<1024) so no memset dispatch is needed.
__global__ __launch_bounds__(256) void pack_weights(
    const float* __restrict__ w, unsigned* __restrict__ wpk,
    float* __restrict__ wsz)
{
    int gid = blockIdx.x * 256 + threadIdx.x;
    if (gid < 1024) wsz[gid] = 0.f;
    if (gid >= 1792) return;
    int lane = gid & 63;
    int rest = gid >> 6;
    int t  = rest % 7;
    int hh = rest / 7;
    int h  = hh >> 1, hl = hh & 1;
    int n  = lane & 15, kq = lane >> 4;
    int co = h * 16 + n;
    const float* wp = w + (co * 8 + 2 * kq) * 27;
    unsigned o[4];
    #pragma unroll
    for (int j = 0; j < 4; ++j) {
        int tau = 4 * t + j;
        if (tau >= 27) { o[j] = 0u; continue; }
        float w0 = wp[tau], w1 = wp[27 + tau];
        unsigned short b0 = f2bf(w0), b1 = f2bf(w1);
        if (hl) {
            b0 = f2bf(w0 - bf2f(b0));
            b1 = f2bf(w1 - bf2f(b1));
        }
        o[j] = ((unsigned)b1 << 16) | b0;
    }
    *(i32x4*)(wpk + ((hh * 7 + t) * 64 + lane) * 4) =
        (i32x4){(int)o[0], (int)o[1], (int)o[2], (int)o[3]};
}

__global__ __launch_bounds__(256, 2) void conv_hs_mfma(
    const float* __restrict__ x, const unsigned* __restrict__ wpk,
    const float* __restrict__ bias, float* __restrict__ ws1, float* __restrict__ ws2)
{
    __shared__ unsigned xdw[NROW * RS];   // 28.8 KB: [row 36][swizzled 4e+sw(kq,e)]
    __shared__ float s1b[32], s2b[32];

    const int tid  = threadIdx.x;
    const int lane = tid & 63;
    const int wv   = tid >> 6;          // wave id = z offset within tile
    const int n    = lane & 15;         // MFMA A-row (co) / B-col index
    const int kq   = lane >> 4;         // k-octet: ci pair {2kq, 2kq+1}

    const int blk = blockIdx.x;
    const int b   = blk / 144;
    const int r0  = blk - b * 144;
    const int zb  = r0 / 12;
    const int yb  = r0 - zb * 12;
    const int z0  = zb * 4, y0 = yb * 4;
    const int z   = z0 + wv;

    if (tid < 32) { s1b[tid] = 0.f; s2b[tid] = 0.f; }

    // A fragments: 28 coalesced 16B loads from the precomputed table.
    i32x4 Ah[2][7], Al[2][7];
    #pragma unroll
    for (int h = 0; h < 2; ++h)
        #pragma unroll
        for (int t = 0; t < 7; ++t) {
            Ah[h][t] = *(const i32x4*)(wpk + (((h * 2 + 0) * 7 + t) * 64 + lane) * 4);
            Al[h][t] = *(const i32x4*)(wpk + (((h * 2 + 1) * 7 + t) * 64 + lane) * 4);
        }

    // C/D layout: row(co) = kq*4 + i (+16h), col = n
    float bias_r[8];
    #pragma unroll
    for (int h = 0; h < 2; ++h)
        #pragma unroll
        for (int i = 0; i < 4; ++i)
            bias_r[h * 4 + i] = bias[h * 16 + kq * 4 + i];

    // ---- stage x tile, bf16 ci-pair packed + bank swizzle ----
    {
        const int q = tid & 3;
        const int e = tid >> 2;            // active e < 48
        if (e < 48) {
            const int sw = (q + 2 * (e >> 3)) & 3;
            const float* p0 = x + (b * 8 + 2 * q) * IN3 + e;
            const float* p1 = p0 + IN3;
            unsigned* dst = xdw + e * 4 + sw;
            #pragma unroll
            for (int zr = 0; zr < 6; ++zr) {
                const int gz = min(z0 + zr, IN - 1);
                #pragma unroll
                for (int yr = 0; yr < 6; ++yr) {
                    const int gy = min(y0 + yr, IN - 1);
                    const int off = gz * IN2 + gy * IN;
                    float f0 = p0[off], f1 = p1[off];
                    dst[(zr * 6 + yr) * RS] = ((unsigned)f2bf(f1) << 16) | f2bf(f0);
                }
            }
        }
    }
    __syncthreads();

    float t1[8] = {0, 0, 0, 0, 0, 0, 0, 0};
    float t2[8] = {0, 0, 0, 0, 0, 0, 0, 0};

    if (z < OUTD) {
        const int ymax = min(4, OUTD - y0);
        for (int y = 0; y < ymax; ++y) {
            const unsigned* yp = xdw + (wv * 6 + y) * RS;
            #pragma unroll
            for (int nt = 0; nt < 3; ++nt) {
                const int col = nt * 16 + n;
                const unsigned* pk[3];
                #pragma unroll
                for (int kw = 0; kw < 3; ++kw) {
                    const int e = col + kw;
                    pk[kw] = yp + e * 4 + ((kq + 2 * (e >> 3)) & 3);
                }
                f32x4 a0h = {0, 0, 0, 0}, a0l = {0, 0, 0, 0};
                f32x4 a1h = {0, 0, 0, 0}, a1l = {0, 0, 0, 0};
                #pragma unroll
                for (int t = 0; t < 7; ++t) {
                    unsigned bd[4];
                    #pragma unroll
                    for (int j = 0; j < 4; ++j) {
                        int tau = 4 * t + j; if (tau > 26) tau = 26;   // pad slot: A=0
                        const int kd = tau / 9, kh = (tau % 9) / 3, kw = tau % 3;
                        bd[j] = pk[kw][(kd * 6 + kh) * RS];
                    }
                    v8s B = __builtin_bit_cast(v8s, (i32x4){(int)bd[0], (int)bd[1], (int)bd[2], (int)bd[3]});
                    a0h = __builtin_amdgcn_mfma_f32_16x16x32_bf16(__builtin_bit_cast(v8s, Ah[0][t]), B, a0h, 0, 0, 0);
                    a0l = __builtin_amdgcn_mfma_f32_16x16x32_bf16(__builtin_bit_cast(v8s, Al[0][t]), B, a0l, 0, 0, 0);
                    a1h = __builtin_amdgcn_mfma_f32_16x16x32_bf16(__builtin_bit_cast(v8s, Ah[1][t]), B, a1h, 0, 0, 0);
                    a1l = __builtin_amdgcn_mfma_f32_16x16x32_bf16(__builtin_bit_cast(v8s, Al[1][t]), B, a1l, 0, 0, 0);
                }
                const bool cok = col < OUTD;
                #pragma unroll
                for (int h = 0; h < 2; ++h) {
                    #pragma unroll
                    for (int i = 0; i < 4; ++i) {
                        float ac = h ? (a1h[i] + a1l[i]) : (a0h[i] + a0l[i]);
                        float v = ac + bias_r[h * 4 + i];
                        float u = fminf(fmaxf(v + 3.0f, 0.0f), 6.0f);
                        float hs = v * u * (1.0f / 6.0f);
                        float hm = cok ? hs : 0.f;
                        t1[h * 4 + i] += hm;
                        t2[h * 4 + i] = fmaf(hm, hm, t2[h * 4 + i]);
                    }
                }
            }
        }
    }

    // reduce over the 16 col-lanes (n); channel set is per-(kq,h,i)
    #pragma unroll
    for (int j = 0; j < 8; ++j) {
        #pragma unroll
        for (int k = 1; k < 16; k <<= 1) {
            t1[j] += __shfl_xor(t1[j], k, 64);
            t2[j] += __shfl_xor(t2[j], k, 64);
        }
    }
    if (n == 0) {
        #pragma unroll
        for (int h = 0; h < 2; ++h)
            #pragma unroll
            for (int i = 0; i < 4; ++i) {
                atomicAdd(&s1b[h * 16 + kq * 4 + i], t1[h * 4 + i]);
                atomicAdd(&s2b[h * 16 + kq * 4 + i], t2[h * 4 + i]);
            }
    }
    __syncthreads();
    if (tid < 32)       atomicAdd(&ws1[b * 32 + tid], s1b[tid]);
    else if (tid < 64)  atomicAdd(&ws2[b * 32 + (tid - 32)], s2b[tid - 32]);
}

__global__ __launch_bounds__(512) void gn_finalize(
    const float* __restrict__ ws1, const float* __restrict__ ws2,
    const float* __restrict__ gnw, const float* __restrict__ gnb,
    float* __restrict__ out)
{
    int tid = threadIdx.x;
    int c = tid & 31;
    float s1 = ws1[tid], s2 = ws2[tid];
    float g1 = s1, g2 = s2;
    #pragma unroll
    for (int k = 1; k < 8; k <<= 1) {
        g1 += __shfl_xor(g1, k, 64);
        g2 += __shfl_xor(g2, k, 64);
    }
    const float Nsp  = 46.0f * 46.0f * 46.0f;
    const float invN = 1.0f / (8.0f * Nsp);
    float mean = g1 * invN;
    float var  = fmaxf(g2 * invN - mean * mean, 0.0f);
    float rstd = rsqrtf(var + 1e-5f);
    float mc   = s1 * (1.0f / Nsp);
    out[tid] = (mc - mean) * rstd * gnw[c] + gnb[c];
}

extern "C" void kernel_launch(void* const* d_in, const int* in_sizes, int n_in,
                              void* d_out, int out_size, void* d_ws, size_t ws_size,
                              hipStream_t stream) {
    const float* x    = (const float*)d_in[0];
    const float* w    = (const float*)d_in[1];
    const float* bias = (const float*)d_in[2];
    const float* gnw  = (const float*)d_in[3];
    const float* gnb  = (const float*)d_in[4];
    float* out = (float*)d_out;
    float* ws1 = (float*)d_ws;
    float* ws2 = ws1 + 512;
    unsigned* wpk = (unsigned*)d_ws + WPK_OFF;   // 14336 dwords

    pack_weights<<<dim3(7), dim3(256), 0, stream>>>(w, wpk, ws1);
    conv_hs_mfma<<<dim3(16 * 12 * 12), dim3(256), 0, stream>>>(x, wpk, bias, ws1, ws2);
    gn_finalize<<<dim3(1), dim3(512), 0, stream>>>(ws1, ws2, gnw, gnb, out);
}

// Round 17
// 141.801 us; speedup vs baseline: 1.3895x; 1.0318x over previous
//
#include <hip/hip_runtime.h>

// Conv3d(8->32, k=3, VALID) + bias + HardSwish + GroupNorm(4) + mean pool.
// R12 (resubmit; container infra failure, never measured) = R11 (proven
// fastest structure: 256 thr, 4z x 4y, 28.8KB LDS, 2304 blocks; conv 73us)
// + tap-major/ci-minor K so each B fragment is ONE contiguous ds_read_b128
// (layout proven correct on HW in R8/R9/R10).
// R11 counter audit: MFMA 24us + LDS-pipe 29us + VALU 23us ~= 73us wall ->
// pipes run serially (dep chain at ~2 waves/SIMD). Fix = fewer instructions
// between MFMAs: per tile 7 b128 + 28 MFMA (was 28 scattered b32 + ~40 VALU
// gather math + 28 MFMA). LDS layout linear (no swizzle needed), staging
// writes stay conflict-free (consecutive dwords per tid).

#define IN 48
#define IN2 2304
#define IN3 110592
#define OUTD 46
#define RS 200            // row stride in dwords (50 e-slots x 4; overread fits)
#define NROW 36           // 6 z-rows x 6 y-rows
#define WPK_OFF 1024      // dword offset of packed-weight table inside ws

typedef short v8s   __attribute__((ext_vector_type(8)));
typedef float f32x4 __attribute__((ext_vector_type(4)));
typedef int   i32x4 __attribute__((ext_vector_type(4)));

__device__ __forceinline__ unsigned short f2bf(float f) {
    unsigned u = __builtin_bit_cast(unsigned, f);
    return (unsigned short)((u + 0x7fffu + ((u >> 16) & 1u)) >> 16);   // RNE
}
__device__ __forceinline__ float bf2f(unsigned short h) {
    unsigned u = ((unsigned)h) << 16;
    return __builtin_bit_cast(float, u);
}

// Tap-major A fragments for 16x16x32 (R8's table, HW-validated).
// Layout: [h][hl][c 0..6][lane][4 dw]. Lane: co_local = lane&15,
// kq = lane>>4 -> tau = 4c+kq; dword j = ci pair {2j, 2j+1}. tau>=27 -> 0.
// Also zeroes ws1/ws2 (gid<1024) so no memset dispatch is needed.
__global__ __launch_bounds__(256) void pack_weights(
    const float* __restrict__ w, unsigned* __restrict__ wpk,
    float* __restrict__ wsz)
{
    int gid = blockIdx.x * 256 + threadIdx.x;
    if (gid < 1024) wsz[gid] = 0.f;
    if (gid >= 1792) return;
    int lane = gid & 63;
    int rest = gid >> 6;          // 0..27
    int c  = rest % 7;
    int hl = (rest / 7) & 1;      // 0 = hi bf16, 1 = lo (residual)
    int h  = rest / 14;           // co half
    int n = lane & 15, kq = lane >> 4;
    int co  = h * 16 + n;
    int tau = 4 * c + kq;
    unsigned o[4];
    #pragma unroll
    for (int j = 0; j < 4; ++j) {
        if (tau >= 27) { o[j] = 0u; continue; }
        float w0 = w[(co * 8 + 2 * j) * 27 + tau];
        float w1 = w[(co * 8 + 2 * j + 1) * 27 + tau];
        unsigned short b0 = f2bf(w0), b1 = f2bf(w1);
        if (hl) {
            b0 = f2bf(w0 - bf2f(b0));
            b1 = f2bf(w1 - bf2f(b1));
        }
        o[j] = ((unsigned)b1 << 16) | b0;
    }
    *(i32x4*)(wpk + (((h * 2 + hl) * 7 + c) * 64 + lane) * 4) =
        (i32x4){(int)o[0], (int)o[1], (int)o[2], (int)o[3]};
}

__global__ __launch_bounds__(256, 2) void conv_hs_mfma(
    const float* __restrict__ x, const unsigned* __restrict__ wpk,
    const float* __restrict__ bias, float* __restrict__ ws1, float* __restrict__ ws2)
{
    __shared__ unsigned xdw[NROW * RS];   // 28.8 KB: [row 36][e*4 + cipair] LINEAR
    __shared__ float s1b[32], s2b[32];

    const int tid  = threadIdx.x;
    const int lane = tid & 63;
    const int wv   = tid >> 6;          // wave id = z offset within tile
    const int n    = lane & 15;         // A-row (co_local) / B-col (x)
    const int kq   = lane >> 4;         // k-quarter -> tap 4c+kq

    const int blk = blockIdx.x;
    const int b   = blk / 144;
    const int r0  = blk - b * 144;
    const int zb  = r0 / 12;
    const int yb  = r0 - zb * 12;
    const int z0  = zb * 4, y0 = yb * 4;
    const int z   = z0 + wv;

    if (tid < 32) { s1b[tid] = 0.f; s2b[tid] = 0.f; }

    // A fragments: 28 coalesced 16B loads from the precomputed table.
    i32x4 Ah[2][7], Al[2][7];
    #pragma unroll
    for (int h = 0; h < 2; ++h)
        #pragma unroll
        for (int c = 0; c < 7; ++c) {
            Ah[h][c] = *(const i32x4*)(wpk + (((h * 2 + 0) * 7 + c) * 64 + lane) * 4);
            Al[h][c] = *(const i32x4*)(wpk + (((h * 2 + 1) * 7 + c) * 64 + lane) * 4);
        }

    // C/D layout: row(co_local) = kq*4 + i (+16h), col = n
    float bias_r[8];
    #pragma unroll
    for (int h = 0; h < 2; ++h)
        #pragma unroll
        for (int i = 0; i < 4; ++i)
            bias_r[h * 4 + i] = bias[h * 16 + kq * 4 + i];

    // Per-lane b128 base per chunk: tau = min(4c+kq, 26) (pad slot -> A=0).
    // byte addr = (wv*6 + kd*6 + kh)*800 + (n + kw)*16; +y*800 +nt*256 in-loop.
    const char* bc[7];
    #pragma unroll
    for (int c = 0; c < 7; ++c) {
        int tau = 4 * c + kq; if (tau > 26) tau = 26;
        const int toff = ((tau / 9) * 6 + ((tau % 9) / 3)) * (RS * 4)
                       + ((tau % 3) + n) * 16;
        bc[c] = (const char*)xdw + wv * (6 * RS * 4) + toff;
    }

    // ---- stage x tile, bf16 ci-pair packed, LINEAR layout ----
    {
        const int q = tid & 3;
        const int e = tid >> 2;            // active e < 48
        if (e < 48) {
            const float* p0 = x + (b * 8 + 2 * q) * IN3 + e;
            const float* p1 = p0 + IN3;
            unsigned* dst = xdw + e * 4 + q;
            #pragma unroll
            for (int zr = 0; zr < 6; ++zr) {
                const int gz = min(z0 + zr, IN - 1);
                #pragma unroll
                for (int yr = 0; yr < 6; ++yr) {
                    const int gy = min(y0 + yr, IN - 1);
                    const int off = gz * IN2 + gy * IN;
                    float f0 = p0[off], f1 = p1[off];
                    dst[(zr * 6 + yr) * RS] = ((unsigned)f2bf(f1) << 16) | f2bf(f0);
                }
            }
        }
    }
    __syncthreads();

    float t1[8] = {0, 0, 0, 0, 0, 0, 0, 0};
    float t2[8] = {0, 0, 0, 0, 0, 0, 0, 0};

    if (z < OUTD) {
        const int ymax = min(4, OUTD - y0);
        for (int y = 0; y < ymax; ++y) {
            const int ybo = y * (RS * 4);
            #pragma unroll
            for (int nt = 0; nt < 3; ++nt) {
                const int col = nt * 16 + n;
                f32x4 a0h = {0, 0, 0, 0}, a0l = {0, 0, 0, 0};
                f32x4 a1h = {0, 0, 0, 0}, a1l = {0, 0, 0, 0};
                #pragma unroll
                for (int c = 0; c < 7; ++c) {
                    i32x4 bd = *(const i32x4*)(bc[c] + ybo + nt * 256);
                    v8s B = __builtin_bit_cast(v8s, bd);
                    a0h = __builtin_amdgcn_mfma_f32_16x16x32_bf16(__builtin_bit_cast(v8s, Ah[0][c]), B, a0h, 0, 0, 0);
                    a1h = __builtin_amdgcn_mfma_f32_16x16x32_bf16(__builtin_bit_cast(v8s, Ah[1][c]), B, a1h, 0, 0, 0);
                    a0l = __builtin_amdgcn_mfma_f32_16x16x32_bf16(__builtin_bit_cast(v8s, Al[0][c]), B, a0l, 0, 0, 0);
                    a1l = __builtin_amdgcn_mfma_f32_16x16x32_bf16(__builtin_bit_cast(v8s, Al[1][c]), B, a1l, 0, 0, 0);
                }
                const bool cok = col < OUTD;
                #pragma unroll
                for (int h = 0; h < 2; ++h) {
                    #pragma unroll
                    for (int i = 0; i < 4; ++i) {
                        float ac = h ? (a1h[i] + a1l[i]) : (a0h[i] + a0l[i]);
                        float v = ac + bias_r[h * 4 + i];
                        float u = fminf(fmaxf(v + 3.0f, 0.0f), 6.0f);
                        float hs = v * u * (1.0f / 6.0f);
                        float hm = cok ? hs : 0.f;
                        t1[h * 4 + i] += hm;
                        t2[h * 4 + i] = fmaf(hm, hm, t2[h * 4 + i]);
                    }
                }
            }
        }
    }

    // reduce over the 16 col-lanes (n); channel set is per-(kq,h,i)
    #pragma unroll
    for (int j = 0; j < 8; ++j) {
        #pragma unroll
        for (int k = 1; k < 16; k <<= 1) {
            t1[j] += __shfl_xor(t1[j], k, 64);
            t2[j] += __shfl_xor(t2[j], k, 64);
        }
    }
    if (n == 0) {
        #pragma unroll
        for (int h = 0; h < 2; ++h)
            #pragma unroll
            for (int i = 0; i < 4; ++i) {
                atomicAdd(&s1b[h * 16 + kq * 4 + i], t1[h * 4 + i]);
                atomicAdd(&s2b[h * 16 + kq * 4 + i], t2[h * 4 + i]);
            }
    }
    __syncthreads();
    if (tid < 32)       atomicAdd(&ws1[b * 32 + tid], s1b[tid]);
    else if (tid < 64)  atomicAdd(&ws2[b * 32 + (tid - 32)], s2b[tid - 32]);
}

__global__ __launch_bounds__(512) void gn_finalize(
    const float* __restrict__ ws1, const float* __restrict__ ws2,
    const float* __restrict__ gnw, const float* __restrict__ gnb,
    float* __restrict__ out)
{
    int tid = threadIdx.x;
    int c = tid & 31;
    float s1 = ws1[tid], s2 = ws2[tid];
    float g1 = s1, g2 = s2;
    #pragma unroll
    for (int k = 1; k < 8; k <<= 1) {
        g1 += __shfl_xor(g1, k, 64);
        g2 += __shfl_xor(g2, k, 64);
    }
    const float Nsp  = 46.0f * 46.0f * 46.0f;
    const float invN = 1.0f / (8.0f * Nsp);
    float mean = g1 * invN;
    float var  = fmaxf(g2 * invN - mean * mean, 0.0f);
    float rstd = rsqrtf(var + 1e-5f);
    float mc   = s1 * (1.0f / Nsp);
    out[tid] = (mc - mean) * rstd * gnw[c] + gnb[c];
}

extern "C" void kernel_launch(void* const* d_in, const int* in_sizes, int n_in,
                              void* d_out, int out_size, void* d_ws, size_t ws_size,
                              hipStream_t stream) {
    const float* x    = (const float*)d_in[0];
    const float* w    = (const float*)d_in[1];
    const float* bias = (const float*)d_in[2];
    const float* gnw  = (const float*)d_in[3];
    const float* gnb  = (const float*)d_in[4];
    float* out = (float*)d_out;
    float* ws1 = (float*)d_ws;
    float* ws2 = ws1 + 512;
    unsigned* wpk = (unsigned*)d_ws + WPK_OFF;   // 7168 dwords

    pack_weights<<<dim3(7), dim3(256), 0, stream>>>(w, wpk, ws1);
    conv_hs_mfma<<<dim3(16 * 12 * 12), dim3(256), 0, stream>>>(x, wpk, bias, ws1, ws2);
    gn_finalize<<<dim3(1), dim3(512), 0, stream>>>(ws1, ws2, gnw, gnb, out);
}